// Round 6
// baseline (841.475 us; speedup 1.0000x reference)
//
#include <hip/hip_runtime.h>
#include <math.h>

#pragma clang fp contract(off)

typedef float v2f __attribute__((ext_vector_type(2)));

#define RR 7
#define HH 2048
#define WW 2048
#define PH 2062
#define PW 2062
#define PITCH 2080
#define PLANE (PITCH * PH)

#define BLK 256
#define WOUT 496        // output cols per block (threads 0..247, 2 cols each)
#define TYB 32          // output rows per block (R3: 16 regressed; keep 32)
#define GX 5            // 5*496 = 2480 >= 2062
#define GY 65           // 65*32 = 2080 >= 2062

__global__ __launch_bounds__(256) void sw_pad(const float* __restrict__ img,
                                              float* __restrict__ dst) {
    int idx = blockIdx.x * blockDim.x + threadIdx.x;
    if (idx >= PW * PH) return;
    int y = idx / PW, x = idx - y * PW;
    int sy = y - RR; sy = sy < 0 ? 0 : (sy > HH - 1 ? HH - 1 : sy);
    int sx = x - RR; sx = sx < 0 ? 0 : (sx > WW - 1 ? WW - 1 : sx);
    const float* p = img + ((long)sy * WW + sx) * 3;
    long o = (long)y * PITCH + x;
    dst[o] = p[0];
    dst[(long)PLANE + o] = p[1];
    dst[2L * PLANE + o] = p[2];
}

__global__ __launch_bounds__(256) void sw_crop(const float* __restrict__ src,
                                               float* __restrict__ out) {
    int idx = blockIdx.x * blockDim.x + threadIdx.x;
    if (idx >= HH * WW) return;
    int y = idx / WW, x = idx - y * WW;
    long o = (long)(y + RR) * PITCH + (x + RR);
    out[(long)idx * 3 + 0] = src[o];
    out[(long)idx * 3 + 1] = src[(long)PLANE + o];
    out[(long)idx * 3 + 2] = src[2L * PLANE + o];
}

__global__ __launch_bounds__(BLK) void sw_iter(const float* __restrict__ src,
                                               float* __restrict__ dst) {
    // [chunk-row 0..3][half 0..1][col-idx 0..255], float4 {o1L,o1R,o1F,x}: 32 KB
    __shared__ float4 lds4[4 * 512];
    const int tid = threadIdx.x;
    const int x0 = blockIdx.x * WOUT;
    const int y0 = blockIdx.y * TYB;
    const int z = blockIdx.z;
    const float* sp = src + (long)z * PLANE;
    float* dp = dst + (long)z * PLANE;

    const int gc0 = x0 - 8 + 2 * tid;
    const bool gok = (gc0 >= 0) && (gc0 < PW);
    const int oc0 = x0 + 2 * tid;
    const bool comp = (tid < WOUT / 2) && (oc0 < PW);

    const float c15 = 1.0f / 15.0f;

    // register ring: input rows (slot = row & 15), packed {even col, odd col}
    v2f xab[16];
#pragma unroll
    for (int i = 0; i < 16; ++i) { xab[i] = (v2f){0.0f, 0.0f}; }

    // warm-up: rows y0-7 .. y0+6
#pragma unroll
    for (int k = 0; k < 14; ++k) {
        const int r = y0 - 7 + k;
        v2f v = (v2f){0.0f, 0.0f};
        if (gok && r >= 0) v = *(const v2f*)(sp + (long)r * PITCH + gc0);
        xab[(k + 9) & 15] = v;
    }

    // prefetch chunk 0's input rows (y0+7 .. y0+10) into registers
    v2f pf[4];
#pragma unroll
    for (int s = 0; s < 4; ++s) {
        const int t = y0 + 7 + s;
        v2f v = (v2f){0.0f, 0.0f};
        if (gok && t < PH) v = *(const v2f*)(sp + (long)t * PITCH + gc0);
        pf[s] = v;
    }

    // outer loop ROLLED (code size: full 8-chunk unroll is ~90 KB >> 32 KB I$).
    // ring slot (16*cc + 4*c4 + s) & 15 == (4*c4 + s) & 15: cc-independent.
#pragma unroll 1
    for (int cc = 0; cc < 2; ++cc) {
        const int ybase = y0 + 16 * cc;
#pragma unroll
        for (int c4 = 0; c4 < 4; ++c4) {
            __syncthreads();   // #1: previous horizontal done with LDS;
                               // prefetch loads have had a full phase to land
            // ---- vertical stage: rows m = ybase+4*c4+s, inputs from pf[] ----
#pragma unroll
            for (int s = 0; s < 4; ++s) {
                const int jm = (4 * c4 + s) & 15;
                xab[(jm + 7) & 15] = pf[s];

                v2f aL = 0.125f * xab[(jm + 9) & 15];
#pragma unroll
                for (int k = 1; k < 8; ++k) {
                    aL = aL + 0.125f * xab[(jm + 9 + k) & 15];
                }
                v2f aR = 0.125f * xab[jm & 15];       // tap k=7 = row m
#pragma unroll
                for (int k = 8; k < 15; ++k) {
                    aR = aR + 0.125f * xab[(jm + 9 + k) & 15];
                }
                v2f aF = c15 * xab[(jm + 9) & 15];
#pragma unroll
                for (int k = 1; k < 15; ++k) {
                    aF = aF + c15 * xab[(jm + 9 + k) & 15];
                }
                const v2f X = xab[jm & 15];
                lds4[s * 512 + tid]       = make_float4(aL.x, aR.x, aF.x, X.x);
                lds4[s * 512 + 256 + tid] = make_float4(aL.y, aR.y, aF.y, X.y);
            }
            __syncthreads();   // #2: LDS rows ready

            // ---- prefetch next chunk's rows: horizontal phase hides latency ----
            if (4 * cc + c4 + 1 < 8) {
#pragma unroll
                for (int s = 0; s < 4; ++s) {
                    const int t = ybase + 4 * (c4 + 1) + 7 + s;
                    v2f v = (v2f){0.0f, 0.0f};
                    if (gok && t < PH) v = *(const v2f*)(sp + (long)t * PITCH + gc0);
                    pf[s] = v;
                }
            }

            // ---- horizontal stage ----
            if (comp) {
#pragma unroll 1
                for (int s = 0; s < 4; ++s) {
                    const int m = ybase + 4 * c4 + s;
                    if (m >= PH) break;
                    const float4* rowb = lds4 + s * 512;
                    const float4* Eb = rowb + tid + 1;        // even cols 2t+2+2k
                    const float4* Ob = rowb + 256 + tid;      // odd cols 2t+1+2k

                    // 16 taps j=0..15: pixel0 uses taps j (i=j, 0..14),
                    // pixel1 uses taps j (i=j-1, j=1..15).
                    // xy chains (vL,vR) pk-packed per pixel as before.
                    // z chains (vF) pk-packed ACROSS pixels: lane0=p0, lane1=p1.
                    // p1 z-init via add-to-zero at j=1 (exact: values >= +0).
                    // Per-component order/rounding identical to verified R4/R5.
                    v2f a0L, a0R, f0, a1L, a1R, f1;
                    v2f zL, zR;
                    float xc0, xc1;
                    // j=0: q=Ob[0]; p0 i=0
                    {
                        float4 q = Ob[0];
                        v2f qxy = {q.x, q.y};
                        a0L = 0.125f * qxy;
                        f0 = c15 * qxy;
                        zL = (v2f){0.125f * q.z, 0.0f};
                    }
                    // j=1: q=Eb[0]; p0 i=1; p1 i=0 (init)
                    {
                        float4 q = Eb[0];
                        v2f qxy = {q.x, q.y};
                        a0L = a0L + 0.125f * qxy; f0 = f0 + c15 * qxy;
                        a1L = 0.125f * qxy;       f1 = c15 * qxy;
                        v2f qzz = {q.z, q.z};
                        zL = zL + 0.125f * qzz;   // lane1: 0 + t = t (exact init)
                    }
                    // j=2..6: both pixels aL+f adds; z pk adds
#pragma unroll
                    for (int j = 2; j <= 6; ++j) {
                        float4 q = (j & 1) ? Eb[(j - 1) >> 1] : Ob[j >> 1];
                        v2f qxy = {q.x, q.y};
                        a0L = a0L + 0.125f * qxy; f0 = f0 + c15 * qxy;
                        a1L = a1L + 0.125f * qxy; f1 = f1 + c15 * qxy;
                        v2f qzz = {q.z, q.z};
                        zL = zL + 0.125f * qzz;
                    }
                    // j=7: q=Eb[3]; p0 i=7 (aL add, aR init, xc0); p1 i=6
                    {
                        float4 q = Eb[3];
                        v2f qxy = {q.x, q.y};
                        a0L = a0L + 0.125f * qxy; f0 = f0 + c15 * qxy;
                        a0R = 0.125f * qxy;       xc0 = q.w;
                        a1L = a1L + 0.125f * qxy; f1 = f1 + c15 * qxy;
                        v2f qzz = {q.z, q.z};
                        zL = zL + 0.125f * qzz;
                        zR.x = 0.125f * q.z;      // p0 aRz init
                    }
                    // j=8: q=Ob[4]; p0 i=8 (aR add); p1 i=7 (aL add, aR init, xc1)
                    {
                        float4 q = Ob[4];
                        v2f qxy = {q.x, q.y};
                        a0R = a0R + 0.125f * qxy; f0 = f0 + c15 * qxy;
                        a1L = a1L + 0.125f * qxy; f1 = f1 + c15 * qxy;
                        a1R = 0.125f * qxy;       xc1 = q.w;
                        float t = 0.125f * q.z;
                        zR.x = zR.x + t;          // p0 aRz add (i=8)
                        zL.y = zL.y + t;          // p1 aLz add (i=7)
                        zR.y = t;                 // p1 aRz init (i=7)
                    }
                    // j=9..14: both pixels aR+f adds; z pk adds
#pragma unroll
                    for (int j = 9; j <= 14; ++j) {
                        float4 q = (j & 1) ? Eb[(j - 1) >> 1] : Ob[j >> 1];
                        v2f qxy = {q.x, q.y};
                        a0R = a0R + 0.125f * qxy; f0 = f0 + c15 * qxy;
                        a1R = a1R + 0.125f * qxy; f1 = f1 + c15 * qxy;
                        v2f qzz = {q.z, q.z};
                        zR = zR + 0.125f * qzz;
                    }
                    // j=15: q=Eb[7]; p1 i=14 only
                    {
                        float4 q = Eb[7];
                        v2f qxy = {q.x, q.y};
                        a1R = a1R + 0.125f * qxy; f1 = f1 + c15 * qxy;
                        zR.y = zR.y + 0.125f * q.z;
                    }

                    // argmin: d-values via pk subs (lane-wise identical to scalar);
                    // candidate ORDER identical to verified baseline.
                    v2f xcz = {xc0, xc1};
                    v2f dzL = zL - xcz, dzR = zR - xcz;

                    v2f xc0p = {xc0, xc0};
                    v2f dL = a0L - xc0p, dR = a0R - xc0p, dF = f0 - xc0p;
                    float d0 = dL.x, d1 = dR.x, d2 = dL.y, d3 = dR.y;
                    float d4 = dF.x, d5 = dF.y, d6 = dzL.x, d7 = dzR.x;
                    float best = d0, ba = fabsf(d0), a;
                    a = fabsf(d1); if (a < ba) { ba = a; best = d1; }
                    a = fabsf(d2); if (a < ba) { ba = a; best = d2; }
                    a = fabsf(d3); if (a < ba) { ba = a; best = d3; }
                    a = fabsf(d4); if (a < ba) { ba = a; best = d4; }
                    a = fabsf(d5); if (a < ba) { ba = a; best = d5; }
                    a = fabsf(d6); if (a < ba) { ba = a; best = d6; }
                    a = fabsf(d7); if (a < ba) { ba = a; best = d7; }
                    float out0 = xc0 + best;

                    v2f xc1p = {xc1, xc1};
                    dL = a1L - xc1p; dR = a1R - xc1p; dF = f1 - xc1p;
                    d0 = dL.x; d1 = dR.x; d2 = dL.y; d3 = dR.y;
                    d4 = dF.x; d5 = dF.y; d6 = dzL.y; d7 = dzR.y;
                    best = d0; ba = fabsf(d0);
                    a = fabsf(d1); if (a < ba) { ba = a; best = d1; }
                    a = fabsf(d2); if (a < ba) { ba = a; best = d2; }
                    a = fabsf(d3); if (a < ba) { ba = a; best = d3; }
                    a = fabsf(d4); if (a < ba) { ba = a; best = d4; }
                    a = fabsf(d5); if (a < ba) { ba = a; best = d5; }
                    a = fabsf(d6); if (a < ba) { ba = a; best = d6; }
                    a = fabsf(d7); if (a < ba) { ba = a; best = d7; }
                    float out1 = xc1 + best;

                    *(float2*)(dp + (long)m * PITCH + oc0) = make_float2(out0, out1);
                }
            }
        }
    }
}

extern "C" void kernel_launch(void* const* d_in, const int* in_sizes, int n_in,
                              void* d_out, int out_size, void* d_ws, size_t ws_size,
                              hipStream_t stream) {
    (void)in_sizes; (void)n_in; (void)out_size; (void)ws_size;
    const float* img = (const float*)d_in[0];
    float* out = (float*)d_out;
    float* A = (float*)d_ws;
    float* B = A + 3L * PLANE;

    {
        int total = PW * PH;
        int g = (total + 255) / 256;
        sw_pad<<<dim3(g), dim3(256), 0, stream>>>(img, A);
    }
    dim3 grid(GX, GY, 3), block(BLK);
    for (int i = 0; i < 10; ++i) {
        const float* s = (i & 1) ? B : A;
        float* d = (i & 1) ? A : B;
        sw_iter<<<grid, block, 0, stream>>>(s, d);
    }
    // iter 9 (odd) writes A: final state in A.
    {
        int total = HH * WW;
        int g = (total + 255) / 256;
        sw_crop<<<dim3(g), dim3(256), 0, stream>>>(A, out);
    }
}

// Round 7
// 838.928 us; speedup vs baseline: 1.0030x; 1.0030x over previous
//
#include <hip/hip_runtime.h>
#include <math.h>

#pragma clang fp contract(off)

typedef float v2f __attribute__((ext_vector_type(2)));

#define RR 7
#define HH 2048
#define WW 2048
#define PH 2062
#define PW 2062
#define PITCH 2080
#define PLANE (PITCH * PH)

#define BLK 256
#define WVOUT 112       // output cols per wave (56 lanes x 2); 128 staged - 16 halo
#define BWOUT 448       // block output cols = 4 waves * 112
#define TYB 32          // output rows per block (R3: 16 regressed; keep 32)
#define GX 5            // 5*448 = 2240 >= 2062
#define GY 65           // 65*32 = 2080 >= 2062

__global__ __launch_bounds__(256) void sw_pad(const float* __restrict__ img,
                                              float* __restrict__ dst) {
    int idx = blockIdx.x * blockDim.x + threadIdx.x;
    if (idx >= PW * PH) return;
    int y = idx / PW, x = idx - y * PW;
    int sy = y - RR; sy = sy < 0 ? 0 : (sy > HH - 1 ? HH - 1 : sy);
    int sx = x - RR; sx = sx < 0 ? 0 : (sx > WW - 1 ? WW - 1 : sx);
    const float* p = img + ((long)sy * WW + sx) * 3;
    long o = (long)y * PITCH + x;
    dst[o] = p[0];
    dst[(long)PLANE + o] = p[1];
    dst[2L * PLANE + o] = p[2];
}

__global__ __launch_bounds__(256) void sw_crop(const float* __restrict__ src,
                                               float* __restrict__ out) {
    int idx = blockIdx.x * blockDim.x + threadIdx.x;
    if (idx >= HH * WW) return;
    int y = idx / WW, x = idx - y * WW;
    long o = (long)(y + RR) * PITCH + (x + RR);
    out[(long)idx * 3 + 0] = src[o];
    out[(long)idx * 3 + 1] = src[(long)PLANE + o];
    out[(long)idx * 3 + 2] = src[2L * PLANE + o];
}

__global__ __launch_bounds__(BLK) void sw_iter(const float* __restrict__ src,
                                               float* __restrict__ dst) {
    // Wave-autonomous: each wave stages 128 cols (2/lane) and outputs 112.
    // LDS slice is wave-private: [wave][row s 0..3][even 64 | odd 64] float4.
    // NO __syncthreads anywhere: DS ops within a wave are processed in issue
    // order (wave-synchronous LDS); defensive lgkmcnt(0)+sched_barrier between
    // the write phase and the read phase (rule #18).
    __shared__ float4 lds4[4 * 512];   // 32 KB total, 8 KB per wave
    const int tid = threadIdx.x;
    const int w = tid >> 6, l = tid & 63;
    const int x0 = blockIdx.x * BWOUT;
    const int xw0 = x0 + WVOUT * w;
    const int y0 = blockIdx.y * TYB;
    const int z = blockIdx.z;
    const float* sp = src + (long)z * PLANE;
    float* dp = dst + (long)z * PLANE;

    const int gc0 = xw0 - 8 + 2 * l;          // this lane's even staged col
    const bool gok = (gc0 >= 0) && (gc0 < PW);
    const int oc0 = xw0 + 2 * l;              // this lane's even output col
    const bool comp = (l < WVOUT / 2) && (oc0 < PW);

    const float c15 = 1.0f / 15.0f;
    float4* const wbase = lds4 + w * 512;     // wave-private 8 KB slice

    // register ring: input rows (slot = row & 15), packed {even col, odd col}
    v2f xab[16];
#pragma unroll
    for (int i = 0; i < 16; ++i) { xab[i] = (v2f){0.0f, 0.0f}; }

    // warm-up: rows y0-7 .. y0+6
#pragma unroll
    for (int k = 0; k < 14; ++k) {
        const int r = y0 - 7 + k;
        v2f v = (v2f){0.0f, 0.0f};
        if (gok && r >= 0) v = *(const v2f*)(sp + (long)r * PITCH + gc0);
        xab[(k + 9) & 15] = v;
    }

    // prefetch chunk 0's input rows (y0+7 .. y0+10) into registers
    v2f pf[4];
#pragma unroll
    for (int s = 0; s < 4; ++s) {
        const int t = y0 + 7 + s;
        v2f v = (v2f){0.0f, 0.0f};
        if (gok && t < PH) v = *(const v2f*)(sp + (long)t * PITCH + gc0);
        pf[s] = v;
    }

    // outer loop ROLLED (I$: full unroll would be ~2x the 32 KB I$).
    // ring slot (16*cc + 4*c4 + s) & 15 == (4*c4 + s) & 15: cc-independent.
#pragma unroll 1
    for (int cc = 0; cc < 2; ++cc) {
        const int ybase = y0 + 16 * cc;
#pragma unroll
        for (int c4 = 0; c4 < 4; ++c4) {
            // ---- vertical stage: rows m = ybase+4*c4+s, inputs from pf[] ----
#pragma unroll
            for (int s = 0; s < 4; ++s) {
                const int jm = (4 * c4 + s) & 15;
                xab[(jm + 7) & 15] = pf[s];

                v2f aL = 0.125f * xab[(jm + 9) & 15];
#pragma unroll
                for (int k = 1; k < 8; ++k) {
                    aL = aL + 0.125f * xab[(jm + 9 + k) & 15];
                }
                v2f aR = 0.125f * xab[jm & 15];       // tap k=7 = row m
#pragma unroll
                for (int k = 8; k < 15; ++k) {
                    aR = aR + 0.125f * xab[(jm + 9 + k) & 15];
                }
                v2f aF = c15 * xab[(jm + 9) & 15];
#pragma unroll
                for (int k = 1; k < 15; ++k) {
                    aF = aF + c15 * xab[(jm + 9 + k) & 15];
                }
                const v2f X = xab[jm & 15];
                wbase[s * 128 + l]      = make_float4(aL.x, aR.x, aF.x, X.x); // even
                wbase[s * 128 + 64 + l] = make_float4(aL.y, aR.y, aF.y, X.y); // odd
            }
            // wave-sync: ensure our ds_writes land before neighbor-lane reads.
            asm volatile("s_waitcnt lgkmcnt(0)" ::: "memory");
            __builtin_amdgcn_sched_barrier(0);

            // ---- prefetch next chunk's rows: horizontal phase hides latency ----
            if (4 * cc + c4 + 1 < 8) {
#pragma unroll
                for (int s = 0; s < 4; ++s) {
                    const int t = ybase + 4 * (c4 + 1) + 7 + s;
                    v2f v = (v2f){0.0f, 0.0f};
                    if (gok && t < PH) v = *(const v2f*)(sp + (long)t * PITCH + gc0);
                    pf[s] = v;
                }
            }

            // ---- horizontal stage (wave-private LDS reads) ----
            if (comp) {
#pragma unroll 1
                for (int s = 0; s < 4; ++s) {
                    const int m = ybase + 4 * c4 + s;
                    if (m >= PH) break;
                    const float4* rowb = wbase + s * 128;
                    const float4* Eb = rowb + l + 1;      // even cols oc0-6+2k
                    const float4* Ob = rowb + 64 + l;     // odd cols  oc0-7+2k

                    // 16 taps j=0..15 ascending cols oc0-7..oc0+8.
                    // xy chains pk-packed per pixel; z chains pk-packed ACROSS
                    // pixels (lane0=p0, lane1=p1; p1 init via exact add-to-zero).
                    // Per-component order/rounding identical to verified R4-R6.
                    v2f a0L, a0R, f0, a1L, a1R, f1;
                    v2f zL, zR;
                    float xc0, xc1;
                    // j=0: q=Ob[0]; p0 i=0
                    {
                        float4 q = Ob[0];
                        v2f qxy = {q.x, q.y};
                        a0L = 0.125f * qxy;
                        f0 = c15 * qxy;
                        zL = (v2f){0.125f * q.z, 0.0f};
                    }
                    // j=1: q=Eb[0]; p0 i=1; p1 i=0 (init)
                    {
                        float4 q = Eb[0];
                        v2f qxy = {q.x, q.y};
                        a0L = a0L + 0.125f * qxy; f0 = f0 + c15 * qxy;
                        a1L = 0.125f * qxy;       f1 = c15 * qxy;
                        v2f qzz = {q.z, q.z};
                        zL = zL + 0.125f * qzz;   // lane1: 0 + t = t (exact init)
                    }
                    // j=2..6: both pixels aL+f adds; z pk adds
#pragma unroll
                    for (int j = 2; j <= 6; ++j) {
                        float4 q = (j & 1) ? Eb[(j - 1) >> 1] : Ob[j >> 1];
                        v2f qxy = {q.x, q.y};
                        a0L = a0L + 0.125f * qxy; f0 = f0 + c15 * qxy;
                        a1L = a1L + 0.125f * qxy; f1 = f1 + c15 * qxy;
                        v2f qzz = {q.z, q.z};
                        zL = zL + 0.125f * qzz;
                    }
                    // j=7: q=Eb[3]; p0 i=7 (aL add, aR init, xc0); p1 i=6
                    {
                        float4 q = Eb[3];
                        v2f qxy = {q.x, q.y};
                        a0L = a0L + 0.125f * qxy; f0 = f0 + c15 * qxy;
                        a0R = 0.125f * qxy;       xc0 = q.w;
                        a1L = a1L + 0.125f * qxy; f1 = f1 + c15 * qxy;
                        v2f qzz = {q.z, q.z};
                        zL = zL + 0.125f * qzz;
                        zR.x = 0.125f * q.z;      // p0 aRz init
                    }
                    // j=8: q=Ob[4]; p0 i=8 (aR add); p1 i=7 (aL add, aR init, xc1)
                    {
                        float4 q = Ob[4];
                        v2f qxy = {q.x, q.y};
                        a0R = a0R + 0.125f * qxy; f0 = f0 + c15 * qxy;
                        a1L = a1L + 0.125f * qxy; f1 = f1 + c15 * qxy;
                        a1R = 0.125f * qxy;       xc1 = q.w;
                        float t = 0.125f * q.z;
                        zR.x = zR.x + t;          // p0 aRz add (i=8)
                        zL.y = zL.y + t;          // p1 aLz add (i=7)
                        zR.y = t;                 // p1 aRz init (i=7)
                    }
                    // j=9..14: both pixels aR+f adds; z pk adds
#pragma unroll
                    for (int j = 9; j <= 14; ++j) {
                        float4 q = (j & 1) ? Eb[(j - 1) >> 1] : Ob[j >> 1];
                        v2f qxy = {q.x, q.y};
                        a0R = a0R + 0.125f * qxy; f0 = f0 + c15 * qxy;
                        a1R = a1R + 0.125f * qxy; f1 = f1 + c15 * qxy;
                        v2f qzz = {q.z, q.z};
                        zR = zR + 0.125f * qzz;
                    }
                    // j=15: q=Eb[7]; p1 i=14 only
                    {
                        float4 q = Eb[7];
                        v2f qxy = {q.x, q.y};
                        a1R = a1R + 0.125f * qxy; f1 = f1 + c15 * qxy;
                        zR.y = zR.y + 0.125f * q.z;
                    }

                    // argmin: d-values via pk subs (lane-wise identical to
                    // scalar); candidate ORDER identical to verified baseline.
                    v2f xcz = {xc0, xc1};
                    v2f dzL = zL - xcz, dzR = zR - xcz;

                    v2f xc0p = {xc0, xc0};
                    v2f dL = a0L - xc0p, dR = a0R - xc0p, dF = f0 - xc0p;
                    float d0 = dL.x, d1 = dR.x, d2 = dL.y, d3 = dR.y;
                    float d4 = dF.x, d5 = dF.y, d6 = dzL.x, d7 = dzR.x;
                    float best = d0, ba = fabsf(d0), a;
                    a = fabsf(d1); if (a < ba) { ba = a; best = d1; }
                    a = fabsf(d2); if (a < ba) { ba = a; best = d2; }
                    a = fabsf(d3); if (a < ba) { ba = a; best = d3; }
                    a = fabsf(d4); if (a < ba) { ba = a; best = d4; }
                    a = fabsf(d5); if (a < ba) { ba = a; best = d5; }
                    a = fabsf(d6); if (a < ba) { ba = a; best = d6; }
                    a = fabsf(d7); if (a < ba) { ba = a; best = d7; }
                    float out0 = xc0 + best;

                    v2f xc1p = {xc1, xc1};
                    dL = a1L - xc1p; dR = a1R - xc1p; dF = f1 - xc1p;
                    d0 = dL.x; d1 = dR.x; d2 = dL.y; d3 = dR.y;
                    d4 = dF.x; d5 = dF.y; d6 = dzL.y; d7 = dzR.y;
                    best = d0; ba = fabsf(d0);
                    a = fabsf(d1); if (a < ba) { ba = a; best = d1; }
                    a = fabsf(d2); if (a < ba) { ba = a; best = d2; }
                    a = fabsf(d3); if (a < ba) { ba = a; best = d3; }
                    a = fabsf(d4); if (a < ba) { ba = a; best = d4; }
                    a = fabsf(d5); if (a < ba) { ba = a; best = d5; }
                    a = fabsf(d6); if (a < ba) { ba = a; best = d6; }
                    a = fabsf(d7); if (a < ba) { ba = a; best = d7; }
                    float out1 = xc1 + best;

                    *(float2*)(dp + (long)m * PITCH + oc0) = make_float2(out0, out1);
                }
            }
        }
    }
}

extern "C" void kernel_launch(void* const* d_in, const int* in_sizes, int n_in,
                              void* d_out, int out_size, void* d_ws, size_t ws_size,
                              hipStream_t stream) {
    (void)in_sizes; (void)n_in; (void)out_size; (void)ws_size;
    const float* img = (const float*)d_in[0];
    float* out = (float*)d_out;
    float* A = (float*)d_ws;
    float* B = A + 3L * PLANE;

    {
        int total = PW * PH;
        int g = (total + 255) / 256;
        sw_pad<<<dim3(g), dim3(256), 0, stream>>>(img, A);
    }
    dim3 grid(GX, GY, 3), block(BLK);
    for (int i = 0; i < 10; ++i) {
        const float* s = (i & 1) ? B : A;
        float* d = (i & 1) ? A : B;
        sw_iter<<<grid, block, 0, stream>>>(s, d);
    }
    // iter 9 (odd) writes A: final state in A.
    {
        int total = HH * WW;
        int g = (total + 255) / 256;
        sw_crop<<<dim3(g), dim3(256), 0, stream>>>(A, out);
    }
}